// Round 12
// baseline (227.846 us; speedup 1.0000x reference)
//
#include <hip/hip_runtime.h>
#include <hip/hip_bf16.h>

#define NN   50000
#define EE   1600000
#define FIN  128
#define FOUT 64
#define BETA  0.5f
#define ALPHA 0.2f
#define SBW    256          // src rows per super-bucket
#define NB2    196          // ceil(NN/SBW)
#define RCAP   9000         // fixed region capacity (mean 8163 + ~9 sigma)
#define PGRID  782          // partition blocks (ceil(EE/PCHUNK))
#define PCHUNK 2048         // edges per partition block (8 per thread)
#define CAP2   8192         // csr LDS record cache (64 KB)
#define XS     136          // gemm X LDS stride (bf16 elems, 16B-aligned rows)

typedef __attribute__((ext_vector_type(8))) short short8;
typedef __attribute__((ext_vector_type(8))) unsigned short ushort8v;
typedef __attribute__((ext_vector_type(4))) float float4v;

__device__ __forceinline__ float load_any(const void* p, long i, int isf32) {
    if (isf32) return ((const float*)p)[i];
    unsigned int b = ((unsigned int)(((const unsigned short*)p)[i])) << 16;
    return __uint_as_float(b);
}

__device__ __forceinline__ unsigned short f32_to_bf16_rne(float f) {
    unsigned int b = __float_as_uint(f);
    return (unsigned short)((b + 0x7FFF + ((b >> 16) & 1)) >> 16);
}

__device__ __forceinline__ float bf16_to_f32(unsigned short u) {
    return __uint_as_float(((unsigned int)u) << 16);
}

// ---------------------------------------------------------------------------
// Kernel 0: sampled dtype detection. flags[t]=1 means fp32.
// ---------------------------------------------------------------------------
__global__ __launch_bounds__(256) void detect_kernel(
    const void* inp, const void* Mv, const void* W, const void* a, int* flags)
{
    const void* ptrs[4] = { inp, Mv, W, a };
    const long  cnts[4] = { (long)NN * FIN, (long)EE, (long)FIN * FOUT, 2L * FOUT };
    const int t = blockIdx.x;
    const unsigned short* p = (const unsigned short*)ptrs[t];
    const long half = cnts[t] >> 1;
    long step = half / 256; if (step == 0) step = 1;
    const long pos = 2 * (((long)threadIdx.x * step) % half);

    const float v = bf16_to_f32(p[pos]);
    const int bad = (isnan(v) || fabsf(v) > 1e4f) ? 1 : 0;

    __shared__ int sbad[256];
    sbad[threadIdx.x] = bad;
    __syncthreads();
    for (int s = 128; s > 0; s >>= 1) {
        if (threadIdx.x < (unsigned)s) sbad[threadIdx.x] |= sbad[threadIdx.x + s];
        __syncthreads();
    }
    if (threadIdx.x == 0) flags[t] = sbad[0];
}

// ---------------------------------------------------------------------------
// Kernel 0b: one-time W transpose -> Wt[n][k] bf16 (16 KB).
// ---------------------------------------------------------------------------
__global__ __launch_bounds__(256) void wt_kernel(
    const void* __restrict__ W, const int* __restrict__ flags,
    unsigned short* __restrict__ Wt)
{
    const int fW = flags[2];
    const int i = blockIdx.x * 256 + threadIdx.x;
    if (i < FIN * FOUT) {
        const int k = i >> 6, n = i & 63;           // read W coalesced
        Wt[n * FIN + k] = f32_to_bf16_rne(load_any(W, i, fW));
    }
}

// ---------------------------------------------------------------------------
// Kernel 1: MFMA gemm (R11-validated). 16 rows/block; X staged via one 16 B
// vector load/thread; B-fragments direct from global Wt (L1-hot 16 KB).
// ---------------------------------------------------------------------------
__global__ __launch_bounds__(256) void mfma_gemm_kernel(
    const void* __restrict__ inp,
    const unsigned short* __restrict__ Wt,   // bf16 [64][128]
    const void* __restrict__ a,
    const int* __restrict__ flags,
    unsigned short* __restrict__ h,
    float* __restrict__ s1,
    float* __restrict__ s2)
{
    __shared__ unsigned short Xs[16 * XS];   // 4.25 KB
    __shared__ float part1[4][16];
    __shared__ float part2[4][16];

    const int tid  = threadIdx.x;
    const int wave = tid >> 6;
    const int lane = tid & 63;
    const int quad = lane >> 4;
    const int col  = lane & 15;
    const int rb   = blockIdx.x * 16;

    const int fI = flags[0], fA = flags[3];

    {
        const int r = tid >> 4, k8 = (tid & 15) * 8;
        if (!fI) {
            const unsigned short* src = (const unsigned short*)inp + (long)(rb + r) * FIN + k8;
            *(ushort8v*)&Xs[r * XS + k8] = *(const ushort8v*)src;
        } else {
            const float* src = (const float*)inp + (long)(rb + r) * FIN + k8;
            ushort8v v;
            #pragma unroll
            for (int j = 0; j < 8; ++j) v[j] = f32_to_bf16_rne(src[j]);
            *(ushort8v*)&Xs[r * XS + k8] = v;
        }
    }
    __syncthreads();

    const int nb = wave * 16;
    float4v acc = { 0.f, 0.f, 0.f, 0.f };
    #pragma unroll
    for (int k0 = 0; k0 < FIN; k0 += 32) {
        const short8 af = *(const short8*)&Xs[col * XS + k0 + quad * 8];
        const short8 bf = *(const short8*)&Wt[(long)(nb + col) * FIN + k0 + quad * 8];
        acc = __builtin_amdgcn_mfma_f32_16x16x32_bf16(af, bf, acc, 0, 0, 0);
    }

    #pragma unroll
    for (int r = 0; r < 4; ++r)
        h[(long)(rb + quad * 4 + r) * FOUT + nb + col] = f32_to_bf16_rne(acc[r]);

    const float a1 = load_any(a, nb + col, fA);
    const float a2 = load_any(a, 64 + nb + col, fA);
    #pragma unroll
    for (int r = 0; r < 4; ++r) {
        float v1 = acc[r] * a1;
        float v2 = acc[r] * a2;
        #pragma unroll
        for (int o = 1; o < 16; o <<= 1) {
            v1 += __shfl_xor(v1, o, 64);
            v2 += __shfl_xor(v2, o, 64);
        }
        if (col == 0) {
            part1[wave][quad * 4 + r] = v1;
            part2[wave][quad * 4 + r] = v2;
        }
    }
    __syncthreads();
    if (tid < 16) {
        s1[rb + tid] = part1[0][tid] + part1[1][tid] + part1[2][tid] + part1[3][tid];
        s2[rb + tid] = part2[0][tid] + part2[1][tid] + part2[2][tid] + part2[3][tid];
    }
}

// ---------------------------------------------------------------------------
// Kernel 2: partition into 196 super-buckets with FIXED regions (b*RCAP).
// Batch-of-8 register pipeline: burst-load 8 (src,dst,Mv) triples (kept in
// VGPRs across both passes), LDS-count, reserve one run/bucket, burst the 8
// (s1,s2) gathers, compute, nontemporal-store recs. 782 blocks for latency
// hiding (R11: 400 blocks -> 12% occupancy, latency-bound at 52 us).
// Record: src<<32 | dst<<16 | bf16(edge_e).
// ---------------------------------------------------------------------------
__global__ __launch_bounds__(256) void partition_kernel(
    const int* __restrict__ edge,
    const void* __restrict__ Mv,
    const int* __restrict__ flags,
    const float* __restrict__ s1,
    const float* __restrict__ s2,
    int* __restrict__ bcur,              // [NB2], zeroed; per-bucket count
    unsigned long long* __restrict__ recs)
{
    __shared__ int lcnt[NB2];
    __shared__ int lbase[NB2];
    const int tid = threadIdx.x;
    const int fM = flags[1];
    const int e0 = blockIdx.x * PCHUNK;

    if (tid < NB2) lcnt[tid] = 0;
    __syncthreads();

    int srcs[8], dsts[8];
    float mvs[8];
    if (e0 + PCHUNK <= EE) {               // fast path: all 8 in range
        #pragma unroll
        for (int k = 0; k < 8; ++k) {
            const int e = e0 + tid + 256 * k;
            srcs[k] = edge[e];
            dsts[k] = edge[EE + e];
            mvs[k]  = load_any(Mv, e, fM);
        }
    } else {
        #pragma unroll
        for (int k = 0; k < 8; ++k) {
            const int e = e0 + tid + 256 * k;
            srcs[k] = (e < EE) ? edge[e] : -1;
            dsts[k] = (e < EE) ? edge[EE + e] : 0;
            mvs[k]  = (e < EE) ? load_any(Mv, e, fM) : 0.f;
        }
    }
    #pragma unroll
    for (int k = 0; k < 8; ++k)
        if (srcs[k] >= 0) atomicAdd(&lcnt[srcs[k] >> 8], 1);
    __syncthreads();

    if (tid < NB2) {
        const int c = lcnt[tid];
        const int o = c ? atomicAdd(&bcur[tid], c) : 0;
        lbase[tid] = tid * RCAP + o;
        lcnt[tid] = 0;                 // reuse as rank counter
    }
    __syncthreads();

    float ss1[8], ss2[8];
    #pragma unroll
    for (int k = 0; k < 8; ++k) {
        ss1[k] = (srcs[k] >= 0) ? s1[srcs[k]] : 0.f;
        ss2[k] = (srcs[k] >= 0) ? s2[dsts[k]] : 0.f;
    }
    #pragma unroll
    for (int k = 0; k < 8; ++k) {
        if (srcs[k] < 0) continue;
        const float bias = mvs[k] * BETA + (1.f - BETA);
        const float x  = ss1[k] + bias * ss2[k];
        const float lr = x > 0.f ? x : ALPHA * x;
        const float ee = __expf(lr);
        const int b = srcs[k] >> 8;
        const int r = atomicAdd(&lcnt[b], 1);
        const int pos = lbase[b] + r;
        if (pos < (b + 1) * RCAP)      // graceful guard (P ~ 1e-17)
            __builtin_nontemporal_store(
                ((unsigned long long)(unsigned)srcs[k] << 32)
              | ((unsigned long long)(unsigned)dsts[k] << 16)
              | (unsigned long long)f32_to_bf16_rne(ee), &recs[pos]);
    }
}

// ---------------------------------------------------------------------------
// Kernel 3: per-super-bucket CSR finalize + row ranges.
// ---------------------------------------------------------------------------
__global__ __launch_bounds__(256) void bucket_csr_kernel(
    const int* __restrict__ bcur,
    const unsigned long long* __restrict__ recs,
    unsigned int* __restrict__ pairs,
    int* __restrict__ rowbeg,
    int* __restrict__ rowend)
{
    __shared__ unsigned long long lrec[CAP2];   // 64 KB
    __shared__ int cnt[SBW];
    __shared__ int off[SBW];
    __shared__ int wsum[4];
    const int b    = blockIdx.x;
    const int tid  = threadIdx.x;
    const int wave = tid >> 6;
    const int lane = tid & 63;
    const int rb   = b * SBW;
    const int beg  = b * RCAP;

    int n = bcur[b]; if (n > RCAP) n = RCAP;

    cnt[tid] = 0;
    __syncthreads();

    for (int j = tid; j < n; j += 256) {
        const unsigned long long rec = recs[beg + j];
        if (j < CAP2) lrec[j] = rec;
        atomicAdd(&cnt[(int)(rec >> 32) - rb], 1);
    }
    __syncthreads();

    const int c = cnt[tid];
    int x = c;
    #pragma unroll
    for (int o = 1; o < 64; o <<= 1) {
        int y = __shfl_up(x, o, 64);
        if (lane >= o) x += y;
    }
    if (lane == 63) wsum[wave] = x;
    __syncthreads();
    int wb = 0;
    for (int w = 0; w < wave; ++w) wb += wsum[w];
    const int myoff = wb + x - c;
    off[tid] = myoff;
    const int row = rb + tid;
    if (row < NN) {
        rowbeg[row] = beg + myoff;
        rowend[row] = beg + myoff + c;
    }
    cnt[tid] = 0;
    __syncthreads();

    for (int j = tid; j < n; j += 256) {
        const unsigned long long rec = (j < CAP2) ? lrec[j] : recs[beg + j];
        const int r = (int)(rec >> 32) - rb;
        const int rank = atomicAdd(&cnt[r], 1);
        pairs[beg + off[r] + rank] = (unsigned int)(rec & 0xFFFFFFFFu);
    }
}

// ---------------------------------------------------------------------------
// Kernel 4: CSR-vector SpMM, fused finalize. One wave per src row; 32 lanes
// per edge (ushort2), 2 edges in flight per half, unrolled x8.
// ---------------------------------------------------------------------------
__global__ __launch_bounds__(256) void spmm_kernel(
    const int* __restrict__ rowbeg,
    const int* __restrict__ rowend,
    const unsigned int* __restrict__ pairs,
    const unsigned short* __restrict__ h,   // bf16 [NN, FOUT]
    const int* __restrict__ flags,
    void* __restrict__ out)
{
    const int wave = threadIdx.x >> 6;
    const int lane = threadIdx.x & 63;
    const int half = lane >> 5;
    const int sl   = lane & 31;
    const int row  = blockIdx.x * 4 + wave;

    const int beg = rowbeg[row];
    const int end = rowend[row];

    float acc0 = 0.f, acc1 = 0.f, rsum = 0.f;
    int j = beg;
    for (; j + 15 < end; j += 16) {
        unsigned int u[8];
        ushort2 hv[8];
        #pragma unroll
        for (int k = 0; k < 8; ++k) u[k] = pairs[j + 2 * k + half];
        #pragma unroll
        for (int k = 0; k < 8; ++k)
            hv[k] = *(const ushort2*)&h[(long)(u[k] >> 16) * FOUT + 2 * sl];
        #pragma unroll
        for (int k = 0; k < 8; ++k) {
            const float v = bf16_to_f32((unsigned short)u[k]);
            rsum += v;
            acc0 = fmaf(v, bf16_to_f32(hv[k].x), acc0);
            acc1 = fmaf(v, bf16_to_f32(hv[k].y), acc1);
        }
    }
    for (; j + 1 < end; j += 2) {
        const unsigned int u = pairs[j + half];
        const ushort2 hv = *(const ushort2*)&h[(long)(u >> 16) * FOUT + 2 * sl];
        const float v = bf16_to_f32((unsigned short)u);
        rsum += v;
        acc0 = fmaf(v, bf16_to_f32(hv.x), acc0);
        acc1 = fmaf(v, bf16_to_f32(hv.y), acc1);
    }
    if (j < end && half == 0) {
        const unsigned int u = pairs[j];
        const ushort2 hv = *(const ushort2*)&h[(long)(u >> 16) * FOUT + 2 * sl];
        const float v = bf16_to_f32((unsigned short)u);
        rsum += v;
        acc0 = fmaf(v, bf16_to_f32(hv.x), acc0);
        acc1 = fmaf(v, bf16_to_f32(hv.y), acc1);
    }

    acc0 += __shfl_xor(acc0, 32, 64);
    acc1 += __shfl_xor(acc1, 32, 64);
    rsum += __shfl_xor(rsum, 32, 64);

    if (half == 0) {
        const float inv = 1.f / rsum;
        float q0 = acc0 * inv;
        float q1 = acc1 * inv;
        q0 = q0 > 0.f ? q0 : (__expf(q0) - 1.f);
        q1 = q1 > 0.f ? q1 : (__expf(q1) - 1.f);
        if (flags[0]) {
            float2* o = (float2*)((float*)out + (long)row * FOUT + 2 * sl);
            *o = make_float2(q0, q1);
        } else {
            ushort2* o = (ushort2*)((unsigned short*)out + (long)row * FOUT + 2 * sl);
            *o = make_ushort2(f32_to_bf16_rne(q0), f32_to_bf16_rne(q1));
        }
    }
}

extern "C" void kernel_launch(void* const* d_in, const int* in_sizes, int n_in,
                              void* d_out, int out_size, void* d_ws, size_t ws_size,
                              hipStream_t stream) {
    const void* inp  = d_in[0];
    const void* Mv   = d_in[1];
    const void* W    = d_in[2];
    const void* a    = d_in[3];
    const int*  edge = (const int*)d_in[4];

    // ws: flags | Wt bf16[64*128] | h bf16[NN*64] | s1[NN] | s2[NN] |
    //     rowbeg[NN] | rowend[NN] | bcur[NB2] | pairs u32[NB2*RCAP] | recs u64[NB2*RCAP]
    char* p = (char*)d_ws;
    int*                flags  = (int*)p;            p += 256;
    unsigned short*     Wt     = (unsigned short*)p; p += ((size_t)FOUT * FIN * 2 + 255) / 256 * 256;
    unsigned short*     h      = (unsigned short*)p; p += ((size_t)NN * FOUT * 2 + 255) / 256 * 256;
    float*              s1     = (float*)p;          p += ((size_t)NN * 4 + 255) / 256 * 256;
    float*              s2     = (float*)p;          p += ((size_t)NN * 4 + 255) / 256 * 256;
    int*                rowbeg = (int*)p;            p += ((size_t)NN * 4 + 255) / 256 * 256;
    int*                rowend = (int*)p;            p += ((size_t)NN * 4 + 255) / 256 * 256;
    int*                bcur   = (int*)p;            p += ((size_t)NB2 * 4 + 255) / 256 * 256;
    unsigned int*       pairs  = (unsigned int*)p;   p += ((size_t)NB2 * RCAP * 4 + 255) / 256 * 256;
    unsigned long long* recs   = (unsigned long long*)p;

    detect_kernel<<<4, 256, 0, stream>>>(inp, Mv, W, a, flags);
    hipMemsetAsync(bcur, 0, (size_t)NB2 * sizeof(int), stream);
    wt_kernel<<<(FIN * FOUT + 255) / 256, 256, 0, stream>>>(W, flags, Wt);
    mfma_gemm_kernel<<<NN / 16, 256, 0, stream>>>(inp, Wt, a, flags, h, s1, s2);
    partition_kernel<<<PGRID, 256, 0, stream>>>(edge, Mv, flags, s1, s2, bcur, recs);
    bucket_csr_kernel<<<NB2, 256, 0, stream>>>(bcur, recs, pairs, rowbeg, rowend);
    spmm_kernel<<<NN / 4, 256, 0, stream>>>(rowbeg, rowend, pairs, h, flags, d_out);
}

// Round 13
// 186.771 us; speedup vs baseline: 1.2199x; 1.2199x over previous
//
#include <hip/hip_runtime.h>
#include <hip/hip_bf16.h>

#define NN   50000
#define EE   1600000
#define FIN  128
#define FOUT 64
#define BETA  0.5f
#define ALPHA 0.2f
#define SBW    256          // src rows per super-bucket
#define NB2    196          // ceil(NN/SBW)
#define RCAP   9000         // fixed region capacity (mean 8163 + ~9 sigma)
#define PGRID  400          // partition blocks (run density: 4000/196 ~ 20 recs/run)
#define PCHUNK 4000         // EE/PGRID exact; 4 edges/thread at 1024 threads
#define CAP2   8192         // csr LDS record cache (64 KB)
#define XS     136          // gemm X LDS stride (bf16 elems, 16B-aligned rows)

typedef __attribute__((ext_vector_type(8))) short short8;
typedef __attribute__((ext_vector_type(8))) unsigned short ushort8v;
typedef __attribute__((ext_vector_type(4))) float float4v;

__device__ __forceinline__ float load_any(const void* p, long i, int isf32) {
    if (isf32) return ((const float*)p)[i];
    unsigned int b = ((unsigned int)(((const unsigned short*)p)[i])) << 16;
    return __uint_as_float(b);
}

__device__ __forceinline__ unsigned short f32_to_bf16_rne(float f) {
    unsigned int b = __float_as_uint(f);
    return (unsigned short)((b + 0x7FFF + ((b >> 16) & 1)) >> 16);
}

__device__ __forceinline__ float bf16_to_f32(unsigned short u) {
    return __uint_as_float(((unsigned int)u) << 16);
}

// ---------------------------------------------------------------------------
// Kernel 0: sampled dtype detection. flags[t]=1 means fp32.
// ---------------------------------------------------------------------------
__global__ __launch_bounds__(256) void detect_kernel(
    const void* inp, const void* Mv, const void* W, const void* a, int* flags)
{
    const void* ptrs[4] = { inp, Mv, W, a };
    const long  cnts[4] = { (long)NN * FIN, (long)EE, (long)FIN * FOUT, 2L * FOUT };
    const int t = blockIdx.x;
    const unsigned short* p = (const unsigned short*)ptrs[t];
    const long half = cnts[t] >> 1;
    long step = half / 256; if (step == 0) step = 1;
    const long pos = 2 * (((long)threadIdx.x * step) % half);

    const float v = bf16_to_f32(p[pos]);
    const int bad = (isnan(v) || fabsf(v) > 1e4f) ? 1 : 0;

    __shared__ int sbad[256];
    sbad[threadIdx.x] = bad;
    __syncthreads();
    for (int s = 128; s > 0; s >>= 1) {
        if (threadIdx.x < (unsigned)s) sbad[threadIdx.x] |= sbad[threadIdx.x + s];
        __syncthreads();
    }
    if (threadIdx.x == 0) flags[t] = sbad[0];
}

// ---------------------------------------------------------------------------
// Kernel 0b: one-time W transpose -> Wt[n][k] bf16 (16 KB).
// ---------------------------------------------------------------------------
__global__ __launch_bounds__(256) void wt_kernel(
    const void* __restrict__ W, const int* __restrict__ flags,
    unsigned short* __restrict__ Wt)
{
    const int fW = flags[2];
    const int i = blockIdx.x * 256 + threadIdx.x;
    if (i < FIN * FOUT) {
        const int k = i >> 6, n = i & 63;           // read W coalesced
        Wt[n * FIN + k] = f32_to_bf16_rne(load_any(W, i, fW));
    }
}

// ---------------------------------------------------------------------------
// Kernel 1: MFMA gemm (R11-validated). 16 rows/block; X staged via one 16 B
// vector load/thread; B-fragments direct from global Wt (L1-hot 16 KB).
// ---------------------------------------------------------------------------
__global__ __launch_bounds__(256) void mfma_gemm_kernel(
    const void* __restrict__ inp,
    const unsigned short* __restrict__ Wt,   // bf16 [64][128]
    const void* __restrict__ a,
    const int* __restrict__ flags,
    unsigned short* __restrict__ h,
    float* __restrict__ s1,
    float* __restrict__ s2)
{
    __shared__ unsigned short Xs[16 * XS];   // 4.25 KB
    __shared__ float part1[4][16];
    __shared__ float part2[4][16];

    const int tid  = threadIdx.x;
    const int wave = tid >> 6;
    const int lane = tid & 63;
    const int quad = lane >> 4;
    const int col  = lane & 15;
    const int rb   = blockIdx.x * 16;

    const int fI = flags[0], fA = flags[3];

    {
        const int r = tid >> 4, k8 = (tid & 15) * 8;
        if (!fI) {
            const unsigned short* src = (const unsigned short*)inp + (long)(rb + r) * FIN + k8;
            *(ushort8v*)&Xs[r * XS + k8] = *(const ushort8v*)src;
        } else {
            const float* src = (const float*)inp + (long)(rb + r) * FIN + k8;
            ushort8v v;
            #pragma unroll
            for (int j = 0; j < 8; ++j) v[j] = f32_to_bf16_rne(src[j]);
            *(ushort8v*)&Xs[r * XS + k8] = v;
        }
    }
    __syncthreads();

    const int nb = wave * 16;
    float4v acc = { 0.f, 0.f, 0.f, 0.f };
    #pragma unroll
    for (int k0 = 0; k0 < FIN; k0 += 32) {
        const short8 af = *(const short8*)&Xs[col * XS + k0 + quad * 8];
        const short8 bf = *(const short8*)&Wt[(long)(nb + col) * FIN + k0 + quad * 8];
        acc = __builtin_amdgcn_mfma_f32_16x16x32_bf16(af, bf, acc, 0, 0, 0);
    }

    #pragma unroll
    for (int r = 0; r < 4; ++r)
        h[(long)(rb + quad * 4 + r) * FOUT + nb + col] = f32_to_bf16_rne(acc[r]);

    const float a1 = load_any(a, nb + col, fA);
    const float a2 = load_any(a, 64 + nb + col, fA);
    #pragma unroll
    for (int r = 0; r < 4; ++r) {
        float v1 = acc[r] * a1;
        float v2 = acc[r] * a2;
        #pragma unroll
        for (int o = 1; o < 16; o <<= 1) {
            v1 += __shfl_xor(v1, o, 64);
            v2 += __shfl_xor(v2, o, 64);
        }
        if (col == 0) {
            part1[wave][quad * 4 + r] = v1;
            part2[wave][quad * 4 + r] = v2;
        }
    }
    __syncthreads();
    if (tid < 16) {
        s1[rb + tid] = part1[0][tid] + part1[1][tid] + part1[2][tid] + part1[3][tid];
        s2[rb + tid] = part2[0][tid] + part2[1][tid] + part2[2][tid] + part2[3][tid];
    }
}

// ---------------------------------------------------------------------------
// Kernel 2: partition into 196 super-buckets with FIXED regions (b*RCAP).
// 1024-thread blocks x 400 = 6400 waves (78% chip capacity) for latency
// hiding, while keeping R11's run density (4000/196 ~ 20 recs = 163 B) and
// NORMAL stores (R12 lesson: nontemporal scattered stores bypass L2's
// write coalescing -> 3x write amp). Batch-4 register pipeline.
// Record: src<<32 | dst<<16 | bf16(edge_e).
// ---------------------------------------------------------------------------
__global__ __launch_bounds__(1024) void partition_kernel(
    const int* __restrict__ edge,
    const void* __restrict__ Mv,
    const int* __restrict__ flags,
    const float* __restrict__ s1,
    const float* __restrict__ s2,
    int* __restrict__ bcur,              // [NB2], zeroed; per-bucket count
    unsigned long long* __restrict__ recs)
{
    __shared__ int lcnt[NB2];
    __shared__ int lbase[NB2];
    const int tid = threadIdx.x;
    const int fM = flags[1];
    const int e0 = blockIdx.x * PCHUNK;

    if (tid < NB2) lcnt[tid] = 0;
    __syncthreads();

    // batch-4: e = e0 + tid + 1024*k, k=0..3; 1024*4 >= PCHUNK=4000 (tail-guarded)
    int srcs[4], dsts[4];
    float mvs[4];
    #pragma unroll
    for (int k = 0; k < 4; ++k) {
        const int e = e0 + tid + 1024 * k;
        const bool ok = (tid + 1024 * k) < PCHUNK;
        srcs[k] = ok ? edge[e] : -1;
        dsts[k] = ok ? edge[EE + e] : 0;
        mvs[k]  = ok ? load_any(Mv, e, fM) : 0.f;
    }
    #pragma unroll
    for (int k = 0; k < 4; ++k)
        if (srcs[k] >= 0) atomicAdd(&lcnt[srcs[k] >> 8], 1);
    __syncthreads();

    if (tid < NB2) {
        const int c = lcnt[tid];
        const int o = c ? atomicAdd(&bcur[tid], c) : 0;
        lbase[tid] = tid * RCAP + o;
        lcnt[tid] = 0;                 // reuse as rank counter
    }
    __syncthreads();

    float ss1[4], ss2[4];
    #pragma unroll
    for (int k = 0; k < 4; ++k) {
        ss1[k] = (srcs[k] >= 0) ? s1[srcs[k]] : 0.f;
        ss2[k] = (srcs[k] >= 0) ? s2[dsts[k]] : 0.f;
    }
    #pragma unroll
    for (int k = 0; k < 4; ++k) {
        if (srcs[k] < 0) continue;
        const float bias = mvs[k] * BETA + (1.f - BETA);
        const float x  = ss1[k] + bias * ss2[k];
        const float lr = x > 0.f ? x : ALPHA * x;
        const float ee = __expf(lr);
        const int b = srcs[k] >> 8;
        const int r = atomicAdd(&lcnt[b], 1);
        const int pos = lbase[b] + r;
        if (pos < (b + 1) * RCAP)      // graceful guard (P ~ 1e-17)
            recs[pos] = ((unsigned long long)(unsigned)srcs[k] << 32)
                      | ((unsigned long long)(unsigned)dsts[k] << 16)
                      | (unsigned long long)f32_to_bf16_rne(ee);
    }
}

// ---------------------------------------------------------------------------
// Kernel 3: per-super-bucket CSR finalize + row ranges.
// ---------------------------------------------------------------------------
__global__ __launch_bounds__(256) void bucket_csr_kernel(
    const int* __restrict__ bcur,
    const unsigned long long* __restrict__ recs,
    unsigned int* __restrict__ pairs,
    int* __restrict__ rowbeg,
    int* __restrict__ rowend)
{
    __shared__ unsigned long long lrec[CAP2];   // 64 KB
    __shared__ int cnt[SBW];
    __shared__ int off[SBW];
    __shared__ int wsum[4];
    const int b    = blockIdx.x;
    const int tid  = threadIdx.x;
    const int wave = tid >> 6;
    const int lane = tid & 63;
    const int rb   = b * SBW;
    const int beg  = b * RCAP;

    int n = bcur[b]; if (n > RCAP) n = RCAP;

    cnt[tid] = 0;
    __syncthreads();

    for (int j = tid; j < n; j += 256) {
        const unsigned long long rec = recs[beg + j];
        if (j < CAP2) lrec[j] = rec;
        atomicAdd(&cnt[(int)(rec >> 32) - rb], 1);
    }
    __syncthreads();

    const int c = cnt[tid];
    int x = c;
    #pragma unroll
    for (int o = 1; o < 64; o <<= 1) {
        int y = __shfl_up(x, o, 64);
        if (lane >= o) x += y;
    }
    if (lane == 63) wsum[wave] = x;
    __syncthreads();
    int wb = 0;
    for (int w = 0; w < wave; ++w) wb += wsum[w];
    const int myoff = wb + x - c;
    off[tid] = myoff;
    const int row = rb + tid;
    if (row < NN) {
        rowbeg[row] = beg + myoff;
        rowend[row] = beg + myoff + c;
    }
    cnt[tid] = 0;
    __syncthreads();

    for (int j = tid; j < n; j += 256) {
        const unsigned long long rec = (j < CAP2) ? lrec[j] : recs[beg + j];
        const int r = (int)(rec >> 32) - rb;
        const int rank = atomicAdd(&cnt[r], 1);
        pairs[beg + off[r] + rank] = (unsigned int)(rec & 0xFFFFFFFFu);
    }
}

// ---------------------------------------------------------------------------
// Kernel 4: CSR-vector SpMM, fused finalize. One wave per src row; 32 lanes
// per edge (ushort2), 2 edges in flight per half, unrolled x8.
// ---------------------------------------------------------------------------
__global__ __launch_bounds__(256) void spmm_kernel(
    const int* __restrict__ rowbeg,
    const int* __restrict__ rowend,
    const unsigned int* __restrict__ pairs,
    const unsigned short* __restrict__ h,   // bf16 [NN, FOUT]
    const int* __restrict__ flags,
    void* __restrict__ out)
{
    const int wave = threadIdx.x >> 6;
    const int lane = threadIdx.x & 63;
    const int half = lane >> 5;
    const int sl   = lane & 31;
    const int row  = blockIdx.x * 4 + wave;

    const int beg = rowbeg[row];
    const int end = rowend[row];

    float acc0 = 0.f, acc1 = 0.f, rsum = 0.f;
    int j = beg;
    for (; j + 15 < end; j += 16) {
        unsigned int u[8];
        ushort2 hv[8];
        #pragma unroll
        for (int k = 0; k < 8; ++k) u[k] = pairs[j + 2 * k + half];
        #pragma unroll
        for (int k = 0; k < 8; ++k)
            hv[k] = *(const ushort2*)&h[(long)(u[k] >> 16) * FOUT + 2 * sl];
        #pragma unroll
        for (int k = 0; k < 8; ++k) {
            const float v = bf16_to_f32((unsigned short)u[k]);
            rsum += v;
            acc0 = fmaf(v, bf16_to_f32(hv[k].x), acc0);
            acc1 = fmaf(v, bf16_to_f32(hv[k].y), acc1);
        }
    }
    for (; j + 1 < end; j += 2) {
        const unsigned int u = pairs[j + half];
        const ushort2 hv = *(const ushort2*)&h[(long)(u >> 16) * FOUT + 2 * sl];
        const float v = bf16_to_f32((unsigned short)u);
        rsum += v;
        acc0 = fmaf(v, bf16_to_f32(hv.x), acc0);
        acc1 = fmaf(v, bf16_to_f32(hv.y), acc1);
    }
    if (j < end && half == 0) {
        const unsigned int u = pairs[j];
        const ushort2 hv = *(const ushort2*)&h[(long)(u >> 16) * FOUT + 2 * sl];
        const float v = bf16_to_f32((unsigned short)u);
        rsum += v;
        acc0 = fmaf(v, bf16_to_f32(hv.x), acc0);
        acc1 = fmaf(v, bf16_to_f32(hv.y), acc1);
    }

    acc0 += __shfl_xor(acc0, 32, 64);
    acc1 += __shfl_xor(acc1, 32, 64);
    rsum += __shfl_xor(rsum, 32, 64);

    if (half == 0) {
        const float inv = 1.f / rsum;
        float q0 = acc0 * inv;
        float q1 = acc1 * inv;
        q0 = q0 > 0.f ? q0 : (__expf(q0) - 1.f);
        q1 = q1 > 0.f ? q1 : (__expf(q1) - 1.f);
        if (flags[0]) {
            float2* o = (float2*)((float*)out + (long)row * FOUT + 2 * sl);
            *o = make_float2(q0, q1);
        } else {
            ushort2* o = (ushort2*)((unsigned short*)out + (long)row * FOUT + 2 * sl);
            *o = make_ushort2(f32_to_bf16_rne(q0), f32_to_bf16_rne(q1));
        }
    }
}

extern "C" void kernel_launch(void* const* d_in, const int* in_sizes, int n_in,
                              void* d_out, int out_size, void* d_ws, size_t ws_size,
                              hipStream_t stream) {
    const void* inp  = d_in[0];
    const void* Mv   = d_in[1];
    const void* W    = d_in[2];
    const void* a    = d_in[3];
    const int*  edge = (const int*)d_in[4];

    // ws: flags | Wt bf16[64*128] | h bf16[NN*64] | s1[NN] | s2[NN] |
    //     rowbeg[NN] | rowend[NN] | bcur[NB2] | pairs u32[NB2*RCAP] | recs u64[NB2*RCAP]
    char* p = (char*)d_ws;
    int*                flags  = (int*)p;            p += 256;
    unsigned short*     Wt     = (unsigned short*)p; p += ((size_t)FOUT * FIN * 2 + 255) / 256 * 256;
    unsigned short*     h      = (unsigned short*)p; p += ((size_t)NN * FOUT * 2 + 255) / 256 * 256;
    float*              s1     = (float*)p;          p += ((size_t)NN * 4 + 255) / 256 * 256;
    float*              s2     = (float*)p;          p += ((size_t)NN * 4 + 255) / 256 * 256;
    int*                rowbeg = (int*)p;            p += ((size_t)NN * 4 + 255) / 256 * 256;
    int*                rowend = (int*)p;            p += ((size_t)NN * 4 + 255) / 256 * 256;
    int*                bcur   = (int*)p;            p += ((size_t)NB2 * 4 + 255) / 256 * 256;
    unsigned int*       pairs  = (unsigned int*)p;   p += ((size_t)NB2 * RCAP * 4 + 255) / 256 * 256;
    unsigned long long* recs   = (unsigned long long*)p;

    detect_kernel<<<4, 256, 0, stream>>>(inp, Mv, W, a, flags);
    hipMemsetAsync(bcur, 0, (size_t)NB2 * sizeof(int), stream);
    wt_kernel<<<(FIN * FOUT + 255) / 256, 256, 0, stream>>>(W, flags, Wt);
    mfma_gemm_kernel<<<NN / 16, 256, 0, stream>>>(inp, Wt, a, flags, h, s1, s2);
    partition_kernel<<<PGRID, 1024, 0, stream>>>(edge, Mv, flags, s1, s2, bcur, recs);
    bucket_csr_kernel<<<NB2, 256, 0, stream>>>(bcur, recs, pairs, rowbeg, rowend);
    spmm_kernel<<<NN / 4, 256, 0, stream>>>(rowbeg, rowend, pairs, h, flags, d_out);
}

// Round 14
// 179.010 us; speedup vs baseline: 1.2728x; 1.0434x over previous
//
#include <hip/hip_runtime.h>
#include <hip/hip_bf16.h>

#define NN   50000
#define EE   1600000
#define FIN  128
#define FOUT 64
#define BETA  0.5f
#define ALPHA 0.2f
#define SBW    256          // src rows per super-bucket
#define NB2    196          // ceil(NN/SBW)
#define RCAP   9000         // fixed region capacity (mean 8163 + ~9 sigma)
#define PGRID  400          // partition blocks (run density: 4000/196 ~ 20 recs/run)
#define PCHUNK 4000         // EE/PGRID exact; 4 edges/thread at 1024 threads
#define CAP2   8192         // csr LDS record cache (64 KB)
#define XS     136          // gemm X LDS stride (bf16 elems, 16B-aligned rows)

typedef __attribute__((ext_vector_type(8))) short short8;
typedef __attribute__((ext_vector_type(8))) unsigned short ushort8v;
typedef __attribute__((ext_vector_type(4))) float float4v;

__device__ __forceinline__ float load_any(const void* p, long i, int isf32) {
    if (isf32) return ((const float*)p)[i];
    unsigned int b = ((unsigned int)(((const unsigned short*)p)[i])) << 16;
    return __uint_as_float(b);
}

__device__ __forceinline__ unsigned short f32_to_bf16_rne(float f) {
    unsigned int b = __float_as_uint(f);
    return (unsigned short)((b + 0x7FFF + ((b >> 16) & 1)) >> 16);
}

__device__ __forceinline__ float bf16_to_f32(unsigned short u) {
    return __uint_as_float(((unsigned int)u) << 16);
}

// ---------------------------------------------------------------------------
// Kernel 0: sampled dtype detection. flags[t]=1 means fp32.
// ---------------------------------------------------------------------------
__global__ __launch_bounds__(256) void detect_kernel(
    const void* inp, const void* Mv, const void* W, const void* a, int* flags)
{
    const void* ptrs[4] = { inp, Mv, W, a };
    const long  cnts[4] = { (long)NN * FIN, (long)EE, (long)FIN * FOUT, 2L * FOUT };
    const int t = blockIdx.x;
    const unsigned short* p = (const unsigned short*)ptrs[t];
    const long half = cnts[t] >> 1;
    long step = half / 256; if (step == 0) step = 1;
    const long pos = 2 * (((long)threadIdx.x * step) % half);

    const float v = bf16_to_f32(p[pos]);
    const int bad = (isnan(v) || fabsf(v) > 1e4f) ? 1 : 0;

    __shared__ int sbad[256];
    sbad[threadIdx.x] = bad;
    __syncthreads();
    for (int s = 128; s > 0; s >>= 1) {
        if (threadIdx.x < (unsigned)s) sbad[threadIdx.x] |= sbad[threadIdx.x + s];
        __syncthreads();
    }
    if (threadIdx.x == 0) flags[t] = sbad[0];
}

// ---------------------------------------------------------------------------
// Kernel 0b: one-time W transpose -> Wt[n][k] bf16 (16 KB). Block 0 also
// zeroes bcur (saves the hipMemsetAsync dispatch).
// ---------------------------------------------------------------------------
__global__ __launch_bounds__(256) void wt_kernel(
    const void* __restrict__ W, const int* __restrict__ flags,
    unsigned short* __restrict__ Wt, int* __restrict__ bcur)
{
    if (blockIdx.x == 0 && threadIdx.x < NB2) bcur[threadIdx.x] = 0;
    const int fW = flags[2];
    const int i = blockIdx.x * 256 + threadIdx.x;
    if (i < FIN * FOUT) {
        const int k = i >> 6, n = i & 63;           // read W coalesced
        Wt[n * FIN + k] = f32_to_bf16_rne(load_any(W, i, fW));
    }
}

// ---------------------------------------------------------------------------
// Kernel 1: MFMA gemm (R11-validated). 16 rows/block; X staged via one 16 B
// vector load/thread; B-fragments direct from global Wt (L1-hot 16 KB).
// ---------------------------------------------------------------------------
__global__ __launch_bounds__(256) void mfma_gemm_kernel(
    const void* __restrict__ inp,
    const unsigned short* __restrict__ Wt,   // bf16 [64][128]
    const void* __restrict__ a,
    const int* __restrict__ flags,
    unsigned short* __restrict__ h,
    float* __restrict__ s1,
    float* __restrict__ s2)
{
    __shared__ unsigned short Xs[16 * XS];   // 4.25 KB
    __shared__ float part1[4][16];
    __shared__ float part2[4][16];

    const int tid  = threadIdx.x;
    const int wave = tid >> 6;
    const int lane = tid & 63;
    const int quad = lane >> 4;
    const int col  = lane & 15;
    const int rb   = blockIdx.x * 16;

    const int fI = flags[0], fA = flags[3];

    {
        const int r = tid >> 4, k8 = (tid & 15) * 8;
        if (!fI) {
            const unsigned short* src = (const unsigned short*)inp + (long)(rb + r) * FIN + k8;
            *(ushort8v*)&Xs[r * XS + k8] = *(const ushort8v*)src;
        } else {
            const float* src = (const float*)inp + (long)(rb + r) * FIN + k8;
            ushort8v v;
            #pragma unroll
            for (int j = 0; j < 8; ++j) v[j] = f32_to_bf16_rne(src[j]);
            *(ushort8v*)&Xs[r * XS + k8] = v;
        }
    }
    __syncthreads();

    const int nb = wave * 16;
    float4v acc = { 0.f, 0.f, 0.f, 0.f };
    #pragma unroll
    for (int k0 = 0; k0 < FIN; k0 += 32) {
        const short8 af = *(const short8*)&Xs[col * XS + k0 + quad * 8];
        const short8 bf = *(const short8*)&Wt[(long)(nb + col) * FIN + k0 + quad * 8];
        acc = __builtin_amdgcn_mfma_f32_16x16x32_bf16(af, bf, acc, 0, 0, 0);
    }

    #pragma unroll
    for (int r = 0; r < 4; ++r)
        h[(long)(rb + quad * 4 + r) * FOUT + nb + col] = f32_to_bf16_rne(acc[r]);

    const float a1 = load_any(a, nb + col, fA);
    const float a2 = load_any(a, 64 + nb + col, fA);
    #pragma unroll
    for (int r = 0; r < 4; ++r) {
        float v1 = acc[r] * a1;
        float v2 = acc[r] * a2;
        #pragma unroll
        for (int o = 1; o < 16; o <<= 1) {
            v1 += __shfl_xor(v1, o, 64);
            v2 += __shfl_xor(v2, o, 64);
        }
        if (col == 0) {
            part1[wave][quad * 4 + r] = v1;
            part2[wave][quad * 4 + r] = v2;
        }
    }
    __syncthreads();
    if (tid < 16) {
        s1[rb + tid] = part1[0][tid] + part1[1][tid] + part1[2][tid] + part1[3][tid];
        s2[rb + tid] = part2[0][tid] + part2[1][tid] + part2[2][tid] + part2[3][tid];
    }
}

// ---------------------------------------------------------------------------
// Kernel 2: partition into 196 super-buckets with FIXED regions (b*RCAP).
// 1024-thread blocks x 400 = 6400 waves; R11 run density; normal stores
// (R12 lesson: NT scattered stores bypass L2 write coalescing -> 3x amp).
// Record: src<<32 | dst<<16 | bf16(edge_e).
// ---------------------------------------------------------------------------
__global__ __launch_bounds__(1024) void partition_kernel(
    const int* __restrict__ edge,
    const void* __restrict__ Mv,
    const int* __restrict__ flags,
    const float* __restrict__ s1,
    const float* __restrict__ s2,
    int* __restrict__ bcur,              // [NB2], zeroed; per-bucket count
    unsigned long long* __restrict__ recs)
{
    __shared__ int lcnt[NB2];
    __shared__ int lbase[NB2];
    const int tid = threadIdx.x;
    const int fM = flags[1];
    const int e0 = blockIdx.x * PCHUNK;

    if (tid < NB2) lcnt[tid] = 0;
    __syncthreads();

    int srcs[4], dsts[4];
    float mvs[4];
    #pragma unroll
    for (int k = 0; k < 4; ++k) {
        const int e = e0 + tid + 1024 * k;
        const bool ok = (tid + 1024 * k) < PCHUNK;
        srcs[k] = ok ? edge[e] : -1;
        dsts[k] = ok ? edge[EE + e] : 0;
        mvs[k]  = ok ? load_any(Mv, e, fM) : 0.f;
    }
    #pragma unroll
    for (int k = 0; k < 4; ++k)
        if (srcs[k] >= 0) atomicAdd(&lcnt[srcs[k] >> 8], 1);
    __syncthreads();

    if (tid < NB2) {
        const int c = lcnt[tid];
        const int o = c ? atomicAdd(&bcur[tid], c) : 0;
        lbase[tid] = tid * RCAP + o;
        lcnt[tid] = 0;                 // reuse as rank counter
    }
    __syncthreads();

    float ss1[4], ss2[4];
    #pragma unroll
    for (int k = 0; k < 4; ++k) {
        ss1[k] = (srcs[k] >= 0) ? s1[srcs[k]] : 0.f;
        ss2[k] = (srcs[k] >= 0) ? s2[dsts[k]] : 0.f;
    }
    #pragma unroll
    for (int k = 0; k < 4; ++k) {
        if (srcs[k] < 0) continue;
        const float bias = mvs[k] * BETA + (1.f - BETA);
        const float x  = ss1[k] + bias * ss2[k];
        const float lr = x > 0.f ? x : ALPHA * x;
        const float ee = __expf(lr);
        const int b = srcs[k] >> 8;
        const int r = atomicAdd(&lcnt[b], 1);
        const int pos = lbase[b] + r;
        if (pos < (b + 1) * RCAP)      // graceful guard (P ~ 1e-17)
            recs[pos] = ((unsigned long long)(unsigned)srcs[k] << 32)
                      | ((unsigned long long)(unsigned)dsts[k] << 16)
                      | (unsigned long long)f32_to_bf16_rne(ee);
    }
}

// ---------------------------------------------------------------------------
// Kernel 3: per-super-bucket CSR finalize + row ranges.
// ---------------------------------------------------------------------------
__global__ __launch_bounds__(256) void bucket_csr_kernel(
    const int* __restrict__ bcur,
    const unsigned long long* __restrict__ recs,
    unsigned int* __restrict__ pairs,
    int* __restrict__ rowbeg,
    int* __restrict__ rowend)
{
    __shared__ unsigned long long lrec[CAP2];   // 64 KB
    __shared__ int cnt[SBW];
    __shared__ int off[SBW];
    __shared__ int wsum[4];
    const int b    = blockIdx.x;
    const int tid  = threadIdx.x;
    const int wave = tid >> 6;
    const int lane = tid & 63;
    const int rb   = b * SBW;
    const int beg  = b * RCAP;

    int n = bcur[b]; if (n > RCAP) n = RCAP;

    cnt[tid] = 0;
    __syncthreads();

    for (int j = tid; j < n; j += 256) {
        const unsigned long long rec = recs[beg + j];
        if (j < CAP2) lrec[j] = rec;
        atomicAdd(&cnt[(int)(rec >> 32) - rb], 1);
    }
    __syncthreads();

    const int c = cnt[tid];
    int x = c;
    #pragma unroll
    for (int o = 1; o < 64; o <<= 1) {
        int y = __shfl_up(x, o, 64);
        if (lane >= o) x += y;
    }
    if (lane == 63) wsum[wave] = x;
    __syncthreads();
    int wb = 0;
    for (int w = 0; w < wave; ++w) wb += wsum[w];
    const int myoff = wb + x - c;
    off[tid] = myoff;
    const int row = rb + tid;
    if (row < NN) {
        rowbeg[row] = beg + myoff;
        rowend[row] = beg + myoff + c;
    }
    cnt[tid] = 0;
    __syncthreads();

    for (int j = tid; j < n; j += 256) {
        const unsigned long long rec = (j < CAP2) ? lrec[j] : recs[beg + j];
        const int r = (int)(rec >> 32) - rb;
        const int rank = atomicAdd(&cnt[r], 1);
        pairs[beg + off[r] + rank] = (unsigned int)(rec & 0xFFFFFFFFu);
    }
}

// ---------------------------------------------------------------------------
// Kernel 4: CSR-vector SpMM, fused finalize. One wave per src row; 16 lanes
// per edge (ushort4 = 4 features/lane), 4 edges in flight per wave,
// unrolled x4 (16 edges/iter, 16 independent gathers in flight).
// ---------------------------------------------------------------------------
__global__ __launch_bounds__(256) void spmm_kernel(
    const int* __restrict__ rowbeg,
    const int* __restrict__ rowend,
    const unsigned int* __restrict__ pairs,
    const unsigned short* __restrict__ h,   // bf16 [NN, FOUT]
    const int* __restrict__ flags,
    void* __restrict__ out)
{
    const int wave = threadIdx.x >> 6;
    const int lane = threadIdx.x & 63;
    const int q    = lane >> 4;          // which of 4 in-flight edges
    const int sl   = lane & 15;          // features 4*sl .. 4*sl+3
    const int row  = blockIdx.x * 4 + wave;

    const int beg = rowbeg[row];
    const int end = rowend[row];

    float a0 = 0.f, a1 = 0.f, a2 = 0.f, a3 = 0.f, rsum = 0.f;
    int j = beg;
    for (; j + 15 < end; j += 16) {
        unsigned int u[4];
        ushort4 hv[4];
        #pragma unroll
        for (int k = 0; k < 4; ++k) u[k] = pairs[j + 4 * k + q];
        #pragma unroll
        for (int k = 0; k < 4; ++k)
            hv[k] = *(const ushort4*)&h[(long)(u[k] >> 16) * FOUT + 4 * sl];
        #pragma unroll
        for (int k = 0; k < 4; ++k) {
            const float v = bf16_to_f32((unsigned short)u[k]);
            rsum += v;
            a0 = fmaf(v, bf16_to_f32(hv[k].x), a0);
            a1 = fmaf(v, bf16_to_f32(hv[k].y), a1);
            a2 = fmaf(v, bf16_to_f32(hv[k].z), a2);
            a3 = fmaf(v, bf16_to_f32(hv[k].w), a3);
        }
    }
    for (; j < end; j += 4) {
        if (j + q < end) {
            const unsigned int u = pairs[j + q];
            const ushort4 hv = *(const ushort4*)&h[(long)(u >> 16) * FOUT + 4 * sl];
            const float v = bf16_to_f32((unsigned short)u);
            rsum += v;
            a0 = fmaf(v, bf16_to_f32(hv.x), a0);
            a1 = fmaf(v, bf16_to_f32(hv.y), a1);
            a2 = fmaf(v, bf16_to_f32(hv.z), a2);
            a3 = fmaf(v, bf16_to_f32(hv.w), a3);
        }
    }

    // combine the 4 quads
    #pragma unroll
    for (int o = 16; o < 64; o <<= 1) {
        a0 += __shfl_xor(a0, o, 64);
        a1 += __shfl_xor(a1, o, 64);
        a2 += __shfl_xor(a2, o, 64);
        a3 += __shfl_xor(a3, o, 64);
        rsum += __shfl_xor(rsum, o, 64);
    }

    if (q == 0) {
        const float inv = 1.f / rsum;
        float q0 = a0 * inv, q1 = a1 * inv, q2 = a2 * inv, q3 = a3 * inv;
        q0 = q0 > 0.f ? q0 : (__expf(q0) - 1.f);
        q1 = q1 > 0.f ? q1 : (__expf(q1) - 1.f);
        q2 = q2 > 0.f ? q2 : (__expf(q2) - 1.f);
        q3 = q3 > 0.f ? q3 : (__expf(q3) - 1.f);
        if (flags[0]) {
            float4* o = (float4*)((float*)out + (long)row * FOUT + 4 * sl);
            *o = make_float4(q0, q1, q2, q3);
        } else {
            ushort4* o = (ushort4*)((unsigned short*)out + (long)row * FOUT + 4 * sl);
            *o = make_ushort4(f32_to_bf16_rne(q0), f32_to_bf16_rne(q1),
                              f32_to_bf16_rne(q2), f32_to_bf16_rne(q3));
        }
    }
}

extern "C" void kernel_launch(void* const* d_in, const int* in_sizes, int n_in,
                              void* d_out, int out_size, void* d_ws, size_t ws_size,
                              hipStream_t stream) {
    const void* inp  = d_in[0];
    const void* Mv   = d_in[1];
    const void* W    = d_in[2];
    const void* a    = d_in[3];
    const int*  edge = (const int*)d_in[4];

    // ws: flags | Wt bf16[64*128] | h bf16[NN*64] | s1[NN] | s2[NN] |
    //     rowbeg[NN] | rowend[NN] | bcur[NB2] | pairs u32[NB2*RCAP] | recs u64[NB2*RCAP]
    char* p = (char*)d_ws;
    int*                flags  = (int*)p;            p += 256;
    unsigned short*     Wt     = (unsigned short*)p; p += ((size_t)FOUT * FIN * 2 + 255) / 256 * 256;
    unsigned short*     h      = (unsigned short*)p; p += ((size_t)NN * FOUT * 2 + 255) / 256 * 256;
    float*              s1     = (float*)p;          p += ((size_t)NN * 4 + 255) / 256 * 256;
    float*              s2     = (float*)p;          p += ((size_t)NN * 4 + 255) / 256 * 256;
    int*                rowbeg = (int*)p;            p += ((size_t)NN * 4 + 255) / 256 * 256;
    int*                rowend = (int*)p;            p += ((size_t)NN * 4 + 255) / 256 * 256;
    int*                bcur   = (int*)p;            p += ((size_t)NB2 * 4 + 255) / 256 * 256;
    unsigned int*       pairs  = (unsigned int*)p;   p += ((size_t)NB2 * RCAP * 4 + 255) / 256 * 256;
    unsigned long long* recs   = (unsigned long long*)p;

    detect_kernel<<<4, 256, 0, stream>>>(inp, Mv, W, a, flags);
    wt_kernel<<<(FIN * FOUT + 255) / 256, 256, 0, stream>>>(W, flags, Wt, bcur);
    mfma_gemm_kernel<<<NN / 16, 256, 0, stream>>>(inp, Wt, a, flags, h, s1, s2);
    partition_kernel<<<PGRID, 1024, 0, stream>>>(edge, Mv, flags, s1, s2, bcur, recs);
    bucket_csr_kernel<<<NB2, 256, 0, stream>>>(bcur, recs, pairs, rowbeg, rowend);
    spmm_kernel<<<NN / 4, 256, 0, stream>>>(rowbeg, rowend, pairs, h, flags, d_out);
}